// Round 1
// baseline (820.291 us; speedup 1.0000x reference)
//
#include <hip/hip_runtime.h>

#define NN 50000
#define NE 600000
#define NP 100000
#define DD 128

// ---------------- CSR build ----------------

__global__ __launch_bounds__(256) void k_count(const int* __restrict__ dst, int* __restrict__ deg) {
    int i = blockIdx.x * 256 + threadIdx.x;
    if (i < NE) atomicAdd(&deg[dst[i]], 1);
}

__global__ __launch_bounds__(1024) void k_scan1(const int* __restrict__ deg, int* __restrict__ excl,
                                                int* __restrict__ sums) {
    __shared__ int tmp[1024];
    int t = threadIdx.x;
    int gid = blockIdx.x * 1024 + t;
    int v = (gid < NN) ? deg[gid] : 0;
    tmp[t] = v;
    __syncthreads();
    #pragma unroll
    for (int off = 1; off < 1024; off <<= 1) {
        int u = (t >= off) ? tmp[t - off] : 0;
        __syncthreads();
        tmp[t] += u;
        __syncthreads();
    }
    excl[gid] = tmp[t] - v;                 // exclusive within block
    if (t == 1023) sums[blockIdx.x] = tmp[t];
}

__global__ __launch_bounds__(64) void k_scan2(int* __restrict__ sums) {
    int t = threadIdx.x;                    // one wave
    int v = (t < 49) ? sums[t] : 0;
    int orig = v;
    #pragma unroll
    for (int off = 1; off < 64; off <<= 1) {
        int u = __shfl_up(v, off, 64);
        if (t >= off) v += u;
    }
    if (t < 64) sums[t] = v - orig;         // exclusive
}

__global__ __launch_bounds__(256) void k_scan3(int* __restrict__ row_ptr, const int* __restrict__ sums,
                                               const int* __restrict__ deg, float* __restrict__ inv_deg) {
    int i = blockIdx.x * 256 + threadIdx.x;
    if (i < NN) {
        row_ptr[i] += sums[i >> 10];
        int d = deg[i];
        inv_deg[i] = 1.0f / (float)(d > 1 ? d : 1);
        if (i == 0) row_ptr[NN] = NE;
    }
}

__global__ __launch_bounds__(256) void k_fill(const int* __restrict__ src, const int* __restrict__ dst,
                                              const int* __restrict__ row_ptr, int* __restrict__ cursor,
                                              int* __restrict__ csr) {
    int i = blockIdx.x * 256 + threadIdx.x;
    if (i < NE) {
        int d = dst[i];
        int p = row_ptr[d] + atomicAdd(&cursor[d], 1);
        csr[p] = src[i];
    }
}

// ---------------- mean aggregation: one wave per node ----------------

__global__ __launch_bounds__(256) void k_agg(const float* __restrict__ h, const int* __restrict__ row_ptr,
                                             const int* __restrict__ csr, const float* __restrict__ inv_deg,
                                             float* __restrict__ agg) {
    int wid = (int)((blockIdx.x * 256 + threadIdx.x) >> 6);
    int lane = threadIdx.x & 63;
    if (wid >= NN) return;
    int beg = row_ptr[wid], end = row_ptr[wid + 1];
    float ax = 0.f, ay = 0.f;
    int i = beg;
    for (; i + 2 <= end; i += 2) {           // unroll-2: two independent row loads in flight
        int s0 = csr[i], s1 = csr[i + 1];
        float2 a = ((const float2*)(h + (size_t)s0 * DD))[lane];
        float2 b = ((const float2*)(h + (size_t)s1 * DD))[lane];
        ax += a.x; ay += a.y; ax += b.x; ay += b.y;
    }
    if (i < end) {
        float2 a = ((const float2*)(h + (size_t)csr[i] * DD))[lane];
        ax += a.x; ay += a.y;
    }
    float sc = inv_deg[wid];
    float2 o; o.x = ax * sc; o.y = ay * sc;
    ((float2*)(agg + (size_t)wid * DD))[lane] = o;
}

// ---------------- SAGE layer: hout = relu?(hin@Ws + agg@Wn + b) ----------------
// 128 threads, 32 rows/block. hT/aT staged transposed (pad 36 keeps float4 reads 16B-aligned).
// Thread tile: 4 rows x 8 cols -> 64 FMA per k vs 2 ds_read_b128 -> VALU-bound.

template <int RELU>
__global__ __launch_bounds__(128) void k_layer(const float* __restrict__ hin, const float* __restrict__ agg,
                                               const float* __restrict__ Ws, const float* __restrict__ Wn,
                                               const float* __restrict__ bias, float* __restrict__ hout) {
    __shared__ float hT[128][36];
    __shared__ float aT[128][36];
    int t = threadIdx.x;
    int row0 = blockIdx.x * 32;
    #pragma unroll
    for (int it = 0; it < 8; ++it) {
        int idx = t + it * 128;              // 0..1023 = 32 rows * 32 float4
        int r = idx >> 5, q = idx & 31;
        int row = row0 + r;
        float4 hv = {0, 0, 0, 0}, av = {0, 0, 0, 0};
        if (row < NN) {
            hv = ((const float4*)hin)[(size_t)row * 32 + q];
            av = ((const float4*)agg)[(size_t)row * 32 + q];
        }
        hT[4 * q + 0][r] = hv.x; hT[4 * q + 1][r] = hv.y; hT[4 * q + 2][r] = hv.z; hT[4 * q + 3][r] = hv.w;
        aT[4 * q + 0][r] = av.x; aT[4 * q + 1][r] = av.y; aT[4 * q + 2][r] = av.z; aT[4 * q + 3][r] = av.w;
    }
    __syncthreads();
    int c = t & 15;                          // cols 8c..8c+7
    int g = t >> 4;                          // rows 4g..4g+3
    float acc[4][8];
    #pragma unroll
    for (int i2 = 0; i2 < 4; ++i2)
        #pragma unroll
        for (int j = 0; j < 8; ++j) acc[i2][j] = 0.f;
    const float4* wsp = (const float4*)Ws;
    const float4* wnp = (const float4*)Wn;
    #pragma unroll 2
    for (int k = 0; k < 128; ++k) {
        float4 hk = *(const float4*)&hT[k][4 * g];
        float4 ak = *(const float4*)&aT[k][4 * g];
        float4 w0 = wsp[k * 32 + 2 * c], w1 = wsp[k * 32 + 2 * c + 1];
        float4 u0 = wnp[k * 32 + 2 * c], u1 = wnp[k * 32 + 2 * c + 1];
        float hv[4] = {hk.x, hk.y, hk.z, hk.w};
        float av[4] = {ak.x, ak.y, ak.z, ak.w};
        float wv[8] = {w0.x, w0.y, w0.z, w0.w, w1.x, w1.y, w1.z, w1.w};
        float uv[8] = {u0.x, u0.y, u0.z, u0.w, u1.x, u1.y, u1.z, u1.w};
        #pragma unroll
        for (int i2 = 0; i2 < 4; ++i2)
            #pragma unroll
            for (int j = 0; j < 8; ++j)
                acc[i2][j] = fmaf(hv[i2], wv[j], fmaf(av[i2], uv[j], acc[i2][j]));
    }
    float4 b0 = ((const float4*)bias)[2 * c], b1 = ((const float4*)bias)[2 * c + 1];
    float bv[8] = {b0.x, b0.y, b0.z, b0.w, b1.x, b1.y, b1.z, b1.w};
    #pragma unroll
    for (int i2 = 0; i2 < 4; ++i2) {
        int row = row0 + 4 * g + i2;
        if (row < NN) {
            float o[8];
            #pragma unroll
            for (int j = 0; j < 8; ++j) {
                float v = acc[i2][j] + bv[j];
                if (RELU) v = fmaxf(v, 0.f);
                o[j] = v;
            }
            float4 s0 = {o[0], o[1], o[2], o[3]}, s1 = {o[4], o[5], o[6], o[7]};
            ((float4*)hout)[(size_t)row * 32 + 2 * c] = s0;
            ((float4*)hout)[(size_t)row * 32 + 2 * c + 1] = s1;
        }
    }
}

// ---------------- fused predictor: out = relu(relu(e@Wp1+b1)@Wp2+b2)@Wp3+b3 ----------------

__global__ __launch_bounds__(128) void k_pred(const float* __restrict__ h,
                                              const int* __restrict__ ps, const int* __restrict__ pd,
                                              const int* __restrict__ ns, const int* __restrict__ nd,
                                              const float* __restrict__ Wp1, const float* __restrict__ bp1,
                                              const float* __restrict__ Wp2, const float* __restrict__ bp2,
                                              const float* __restrict__ Wp3, const float* __restrict__ bp3,
                                              float* __restrict__ out) {
    __shared__ float eT[128][36];
    __shared__ float zT[128][36];
    int t = threadIdx.x;
    int row0 = blockIdx.x * 32;
    #pragma unroll
    for (int it = 0; it < 8; ++it) {
        int idx = t + it * 128;
        int r = idx >> 5, q = idx & 31;
        int row = row0 + r;
        int s, d;
        if (row < NP) { s = ps[row]; d = pd[row]; }
        else          { s = ns[row - NP]; d = nd[row - NP]; }
        float4 a = ((const float4*)h)[(size_t)s * 32 + q];
        float4 b = ((const float4*)h)[(size_t)d * 32 + q];
        eT[4 * q + 0][r] = a.x * b.x; eT[4 * q + 1][r] = a.y * b.y;
        eT[4 * q + 2][r] = a.z * b.z; eT[4 * q + 3][r] = a.w * b.w;
    }
    __syncthreads();
    int c = t & 15, g = t >> 4;
    float acc[4][8];
    #pragma unroll
    for (int i2 = 0; i2 < 4; ++i2)
        #pragma unroll
        for (int j = 0; j < 8; ++j) acc[i2][j] = 0.f;
    const float4* w1p = (const float4*)Wp1;
    #pragma unroll 2
    for (int k = 0; k < 128; ++k) {
        float4 ek = *(const float4*)&eT[k][4 * g];
        float4 w0 = w1p[k * 32 + 2 * c], w1 = w1p[k * 32 + 2 * c + 1];
        float ev[4] = {ek.x, ek.y, ek.z, ek.w};
        float wv[8] = {w0.x, w0.y, w0.z, w0.w, w1.x, w1.y, w1.z, w1.w};
        #pragma unroll
        for (int i2 = 0; i2 < 4; ++i2)
            #pragma unroll
            for (int j = 0; j < 8; ++j)
                acc[i2][j] = fmaf(ev[i2], wv[j], acc[i2][j]);
    }
    {   // z1 = relu(acc + bp1) -> zT (transposed)
        float4 b0 = ((const float4*)bp1)[2 * c], b1 = ((const float4*)bp1)[2 * c + 1];
        float bv[8] = {b0.x, b0.y, b0.z, b0.w, b1.x, b1.y, b1.z, b1.w};
        #pragma unroll
        for (int i2 = 0; i2 < 4; ++i2)
            #pragma unroll
            for (int j = 0; j < 8; ++j)
                zT[8 * c + j][4 * g + i2] = fmaxf(acc[i2][j] + bv[j], 0.f);
    }
    __syncthreads();
    float acc2[4][8];
    #pragma unroll
    for (int i2 = 0; i2 < 4; ++i2)
        #pragma unroll
        for (int j = 0; j < 8; ++j) acc2[i2][j] = 0.f;
    const float4* w2p = (const float4*)Wp2;
    #pragma unroll 2
    for (int k = 0; k < 128; ++k) {
        float4 zk = *(const float4*)&zT[k][4 * g];
        float4 w0 = w2p[k * 32 + 2 * c], w1 = w2p[k * 32 + 2 * c + 1];
        float zv[4] = {zk.x, zk.y, zk.z, zk.w};
        float wv[8] = {w0.x, w0.y, w0.z, w0.w, w1.x, w1.y, w1.z, w1.w};
        #pragma unroll
        for (int i2 = 0; i2 < 4; ++i2)
            #pragma unroll
            for (int j = 0; j < 8; ++j)
                acc2[i2][j] = fmaf(zv[i2], wv[j], acc2[i2][j]);
    }
    // z2 = relu(acc2 + bp2); partial dot with Wp3; butterfly-reduce over the 16 c-lanes
    float4 c0 = ((const float4*)bp2)[2 * c], c1 = ((const float4*)bp2)[2 * c + 1];
    float cv[8] = {c0.x, c0.y, c0.z, c0.w, c1.x, c1.y, c1.z, c1.w};
    float4 w30 = ((const float4*)Wp3)[2 * c], w31 = ((const float4*)Wp3)[2 * c + 1];
    float w3v[8] = {w30.x, w30.y, w30.z, w30.w, w31.x, w31.y, w31.z, w31.w};
    float p[4] = {0.f, 0.f, 0.f, 0.f};
    #pragma unroll
    for (int i2 = 0; i2 < 4; ++i2)
        #pragma unroll
        for (int j = 0; j < 8; ++j)
            p[i2] = fmaf(fmaxf(acc2[i2][j] + cv[j], 0.f), w3v[j], p[i2]);
    #pragma unroll
    for (int off = 1; off < 16; off <<= 1) {
        #pragma unroll
        for (int i2 = 0; i2 < 4; ++i2) p[i2] += __shfl_xor(p[i2], off);
    }
    if (c == 0) {
        float bb = bp3[0];
        #pragma unroll
        for (int i2 = 0; i2 < 4; ++i2) out[row0 + 4 * g + i2] = p[i2] + bb;
    }
}

// ---------------- launch ----------------

extern "C" void kernel_launch(void* const* d_in, const int* in_sizes, int n_in,
                              void* d_out, int out_size, void* d_ws, size_t ws_size,
                              hipStream_t stream) {
    const float* x      = (const float*)d_in[0];
    const float* W_self = (const float*)d_in[1];
    const float* W_neigh= (const float*)d_in[2];
    const float* b      = (const float*)d_in[3];
    const float* Wp1    = (const float*)d_in[4];
    const float* bp1    = (const float*)d_in[5];
    const float* Wp2    = (const float*)d_in[6];
    const float* bp2    = (const float*)d_in[7];
    const float* Wp3    = (const float*)d_in[8];
    const float* bp3    = (const float*)d_in[9];
    const int* edge_src = (const int*)d_in[10];
    const int* edge_dst = (const int*)d_in[11];
    const int* pos_src  = (const int*)d_in[12];
    const int* pos_dst  = (const int*)d_in[13];
    const int* neg_src  = (const int*)d_in[14];
    const int* neg_dst  = (const int*)d_in[15];
    float* out = (float*)d_out;

    size_t o = 0;
    char* base = (char*)d_ws;
    auto take = [&](size_t bytes) -> void* {
        void* r = base + o;
        o = (o + bytes + 255) & ~(size_t)255;
        return r;
    };
    int*   deg     = (int*)take(NN * 4);
    int*   cursor  = (int*)take(NN * 4);
    int*   row_ptr = (int*)take(50304 * 4);   // scan1 writes up to 50175; [NN]=50000 used
    int*   sums    = (int*)take(64 * 4);
    int*   csr     = (int*)take(NE * 4);
    float* inv_deg = (float*)take(NN * 4);
    float* aggm    = (float*)take((size_t)NN * DD * 4);
    float* hA      = (float*)take((size_t)NN * DD * 4);
    float* hB      = (float*)take((size_t)NN * DD * 4);
    (void)ws_size; (void)n_in; (void)in_sizes; (void)out_size;

    hipMemsetAsync(deg, 0, NN * 4, stream);
    hipMemsetAsync(cursor, 0, NN * 4, stream);

    k_count<<<(NE + 255) / 256, 256, 0, stream>>>(edge_dst, deg);
    k_scan1<<<49, 1024, 0, stream>>>(deg, row_ptr, sums);
    k_scan2<<<1, 64, 0, stream>>>(sums);
    k_scan3<<<(NN + 255) / 256, 256, 0, stream>>>(row_ptr, sums, deg, inv_deg);
    k_fill<<<(NE + 255) / 256, 256, 0, stream>>>(edge_src, edge_dst, row_ptr, cursor, csr);

    const int aggGrid = (NN + 3) / 4;          // 4 waves/block, wave per node
    const int layGrid = (NN + 31) / 32;

    // layer 0: x -> hA
    k_agg<<<aggGrid, 256, 0, stream>>>(x, row_ptr, csr, inv_deg, aggm);
    k_layer<1><<<layGrid, 128, 0, stream>>>(x, aggm, W_self, W_neigh, b, hA);
    // layer 1: hA -> hB
    k_agg<<<aggGrid, 256, 0, stream>>>(hA, row_ptr, csr, inv_deg, aggm);
    k_layer<1><<<layGrid, 128, 0, stream>>>(hA, aggm, W_self + 16384, W_neigh + 16384, b + 128, hB);
    // layer 2 (no relu): hB -> hA
    k_agg<<<aggGrid, 256, 0, stream>>>(hB, row_ptr, csr, inv_deg, aggm);
    k_layer<0><<<layGrid, 128, 0, stream>>>(hB, aggm, W_self + 32768, W_neigh + 32768, b + 256, hA);

    k_pred<<<(2 * NP) / 32, 128, 0, stream>>>(hA, pos_src, pos_dst, neg_src, neg_dst,
                                              Wp1, bp1, Wp2, bp2, Wp3, bp3, out);
}